// Round 14
// baseline (1664.564 us; speedup 1.0000x reference)
//
#include <hip/hip_runtime.h>
#include <math.h>

#define BATCH   512
#define TSTEPS  3600
#define H       64
#define XCHUNK  16
#define NCHUNK  (TSTEPS / XCHUNK)   // 225
#define CLASSES 5
#define WPB     8                   // 8 waves/block -> 2 waves per SIMD

typedef _Float16 half8 __attribute__((ext_vector_type(8)));
typedef float    f32x4 __attribute__((ext_vector_type(4)));

__device__ __forceinline__ half8 bc_h8(uint4 v) {
    return __builtin_bit_cast(half8, v);
}

__device__ __forceinline__ float fast_sigmoid(float x) {
    float e = __expf(-x);                 // |x| <= ~9 by construction
    return __builtin_amdgcn_rcpf(1.0f + e);
}
__device__ __forceinline__ float fast_tanh(float x) {
    float e = __expf(2.0f * x);           // |2x| <= ~18, no overflow
    return (e - 1.0f) * __builtin_amdgcn_rcpf(e + 1.0f);
}

// R13 MFMA-GEMV per-wave structure, with EIGHT independent batch-waves per
// block (2 per SIMD). R13's counters: MfmaUtil 28 / VALUBusy 22 -> no pipe
// saturated; the 726-cyc wall is the serial chain (LDS RT + 24 MFMA + tail)
// with >500 idle cyc/step per SIMD. A second co-resident wave fills those
// gaps: A's RT + transcendental tail hide under B's MFMA phase and vice
// versa. R12's co-residency failure was DS-pipe saturation at 9 DS
// ops/step (8 KB broadcast reads); this kernel issues 3 DS ops (~2 KB) so
// 8 waves stay far under the DS pipe. No cross-wave coupling: private hl
// slice, no barriers, per-wave VGPR footprint unchanged (84; 2x84 << 512).
__global__ __launch_bounds__(WPB * 64, 1) void gru_mfma_w8_kernel(
    const float* __restrict__ x,      // [B, T, 1]
    const float* __restrict__ w_ih,   // [192, 1]
    const float* __restrict__ w_hh,   // [192, 64]
    const float* __restrict__ b_ih,   // [192]
    const float* __restrict__ b_hh,   // [192]
    const float* __restrict__ w_head, // [5, 64]
    const float* __restrict__ b_head, // [5]
    float* __restrict__ out)          // [B, 5]
{
    __shared__ __align__(16) _Float16 hl[WPB][H];

    const int tid  = threadIdx.x;
    const int wv   = tid >> 6;
    const int lane = tid & 63;
    const int b    = blockIdx.x * WPB + wv;
    const int q    = lane >> 4;      // k-octet / row-tile selector
    const int col  = lane & 15;      // B n-index / D col

    _Float16* hlw = hl[wv];          // private per-wave h buffer

    // --- B fragments: W_hh tiles, f16, B[k=8q+j][n=col] = W[16t+col][32c+8q+j]
    half8 wB[12][2];
#pragma unroll
    for (int t = 0; t < 12; ++t) {
#pragma unroll
        for (int c = 0; c < 2; ++c) {
            const float* wr = w_hh + (16 * t + col) * H + 32 * c + 8 * q;
            half8 f;
#pragma unroll
            for (int j = 0; j < 8; ++j) f[j] = (_Float16)wr[j];
            wB[t][c] = f;
        }
    }

    // gate parameters for hidden index = lane
    const float wih_r = w_ih[lane], wih_z = w_ih[H + lane], wih_n = w_ih[2 * H + lane];
    const float bsr = b_ih[lane] + b_hh[lane];              // merged r bias
    const float bsz = b_ih[H + lane] + b_hh[H + lane];      // merged z bias
    const float bin = b_ih[2 * H + lane];                   // n: keep split,
    const float bhn = b_hh[2 * H + lane];                   // r multiplies bhh_n

    float h_reg = 0.0f;
    const float* xb = x + (size_t)b * TSTEPS;

    // deterministic LDS start state (h0 = 0)
    hlw[lane] = (_Float16)0.0f;
    __asm volatile("" ::: "memory");

    const f32x4 Z = {0.f, 0.f, 0.f, 0.f};

    // x double-buffer
    float xc[XCHUNK], xn[XCHUNK];
#pragma unroll
    for (int k = 0; k < XCHUNK; ++k) xc[k] = xb[k];

    for (int tc = 0; tc < NCHUNK; ++tc) {
        const float* nb = xb + ((tc + 1 < NCHUNK) ? (tc + 1) * XCHUNK : 0);
#pragma unroll
        for (int k = 0; k < XCHUNK; ++k) xn[k] = nb[k];

#pragma unroll
        for (int tt = 0; tt < XCHUNK; ++tt) {
            // publish h as f16; clobber pins store<->load order (TBAA)
            hlw[lane] = (_Float16)h_reg;
            __asm volatile("" ::: "memory");

            // A fragments: h k-octets, 16B each (wave-broadcast per quad)
            const uint4* hp = (const uint4*)hlw;
            const half8 A0 = bc_h8(hp[q]);        // k = 8q..8q+7
            const half8 A1 = bc_h8(hp[4 + q]);    // k = 32+8q..32+8q+7

            const float xt = xc[tt];
            // input-projection terms: off the critical path
            const float ir = fmaf(xt, wih_r, bsr);
            const float iz = fmaf(xt, wih_z, bsz);
            const float in_ = fmaf(xt, wih_n, bin);

#define GEMV(t, d)                                                     \
            d = __builtin_amdgcn_mfma_f32_16x16x32_f16(A0, wB[t][0], Z, 0, 0, 0); \
            d = __builtin_amdgcn_mfma_f32_16x16x32_f16(A1, wB[t][1], d, 0, 0, 0);

            // ---- r tiles first: sigmoid overlaps the z/n MFMAs ----
            f32x4 d0, d1, d2, d3;
            GEMV(0, d0) GEMV(1, d1) GEMV(2, d2) GEMV(3, d3)
            const float ghr = (q < 2) ? (q == 0 ? d0[0] : d1[0])
                                      : (q == 2 ? d2[0] : d3[0]);
            const float r = fast_sigmoid(ir + ghr);

            f32x4 e0, e1, e2, e3;
            GEMV(4, e0) GEMV(5, e1) GEMV(6, e2) GEMV(7, e3)
            const float ghz = (q < 2) ? (q == 0 ? e0[0] : e1[0])
                                      : (q == 2 ? e2[0] : e3[0]);
            const float z = fast_sigmoid(iz + ghz);

            f32x4 g0, g1, g2, g3;
            GEMV(8, g0) GEMV(9, g1) GEMV(10, g2) GEMV(11, g3)
            const float ghn = (q < 2) ? (q == 0 ? g0[0] : g1[0])
                                      : (q == 2 ? g2[0] : g3[0]);
#undef GEMV

            const float n = fast_tanh(in_ + r * (ghn + bhn));
            h_reg = fmaf(z, h_reg - n, n);   // (1-z)*n + z*h
        }

#pragma unroll
        for (int k = 0; k < XCHUNK; ++k) xc[k] = xn[k];
    }

    // ---- head: out[b][c] = w_head[c,:] . h + b_head[c] ----
#pragma unroll
    for (int cc = 0; cc < CLASSES; ++cc) {
        float v = h_reg * w_head[cc * H + lane];
#pragma unroll
        for (int off = 32; off > 0; off >>= 1)
            v += __shfl_down(v, off, 64);
        if (lane == 0) out[b * CLASSES + cc] = v + b_head[cc];
    }
}

extern "C" void kernel_launch(void* const* d_in, const int* in_sizes, int n_in,
                              void* d_out, int out_size, void* d_ws, size_t ws_size,
                              hipStream_t stream) {
    const float* x      = (const float*)d_in[0];
    const float* w_ih   = (const float*)d_in[1];
    const float* w_hh   = (const float*)d_in[2];
    const float* b_ih   = (const float*)d_in[3];
    const float* b_hh   = (const float*)d_in[4];
    const float* w_head = (const float*)d_in[5];
    const float* b_head = (const float*)d_in[6];
    float* out = (float*)d_out;

    gru_mfma_w8_kernel<<<BATCH / WPB, WPB * 64, 0, stream>>>(
        x, w_ih, w_hh, b_ih, b_hh, w_head, b_head, out);
}

// Round 16
// 1139.342 us; speedup vs baseline: 1.4610x; 1.4610x over previous
//
#include <hip/hip_runtime.h>
#include <math.h>

#define BATCH   512
#define TSTEPS  3600
#define H       64
#define XCHUNK  16
#define NCHUNK  (TSTEPS / XCHUNK)   // 225
#define CLASSES 5

typedef _Float16 half8 __attribute__((ext_vector_type(8)));
typedef float    f32x4 __attribute__((ext_vector_type(4)));

#define DPP_WAVE_ROL1 0x134

__device__ __forceinline__ float dpp_rol1(float v) {
    int i = __builtin_bit_cast(int, v);
    return __builtin_bit_cast(float,
        __builtin_amdgcn_update_dpp(i, i, DPP_WAVE_ROL1, 0xF, 0xF, false));
}

__device__ __forceinline__ int pack_f16_pair(float lo, float hi) {
    // v_cvt_pkrtz_f16_f32 -> returns __fp16x2; bit-cast to int for bpermute
    auto p = __builtin_amdgcn_cvt_pkrtz(lo, hi);
    return __builtin_bit_cast(int, p);
}

__device__ __forceinline__ float fast_sigmoid(float x) {
    float e = __expf(-x);                 // |x| <= ~9 by construction
    return __builtin_amdgcn_rcpf(1.0f + e);
}
__device__ __forceinline__ float fast_tanh(float x) {
    float e = __expf(2.0f * x);           // |2x| <= ~18, no overflow
    return (e - 1.0f) * __builtin_amdgcn_rcpf(e + 1.0f);
}

// ONE WAVE per batch, MFMA GEMV, ZERO LDS. R13's 726-cyc chain spent ~160
// on the LDS h round-trip (ds_write_b16 -> in-order DS -> 2 ds_read_b128).
// Here the A-fragment (lane(q,col) needs h-octet {8q..8q+7} as 4 f16-pair
// dwords) is built in REGISTERS: dpp_rol1 + v_cvt_pkrtz pack pair
// {h_i,h_{i+1}} into every lane (needed pairs live at even lanes), then 8
// independent ds_bpermute_b32 (crossbar, no memory, no store->load wait)
// pull the octet dwords. Addresses are loop-invariant per-lane constants.
// MFMA formulation unchanged from R13 (validated 9.8e-4): A[m][k]=h_k,
// B[k][n]=W[16t+col][k], D col=lane&15, 12 tiles x K=64. r-tiles first so
// r's sigmoid hides under z/n MFMAs. No __shared__ -> no replay-state
// (TBAA) hazard class at all. Latency race: 512 serial chains, wall =
// 3600 x per-step chain. Co-residency abandoned (R12/R14: phase-locked
// waves on one SIMD contend ~1.5x, never fill gaps).
__global__ __launch_bounds__(64, 1) void gru_mfma_bp_kernel(
    const float* __restrict__ x,      // [B, T, 1]
    const float* __restrict__ w_ih,   // [192, 1]
    const float* __restrict__ w_hh,   // [192, 64]
    const float* __restrict__ b_ih,   // [192]
    const float* __restrict__ b_hh,   // [192]
    const float* __restrict__ w_head, // [5, 64]
    const float* __restrict__ b_head, // [5]
    float* __restrict__ out)          // [B, 5]
{
    const int lane = threadIdx.x;    // block = 1 wave
    const int b    = blockIdx.x;
    const int q    = lane >> 4;      // k-octet / row-tile selector
    const int col  = lane & 15;      // B n-index / D col

    // --- B fragments: W_hh tiles, f16, B[k=8q+j][n=col] = W[16t+col][32c+8q+j]
    half8 wB[12][2];
#pragma unroll
    for (int t = 0; t < 12; ++t) {
#pragma unroll
        for (int c = 0; c < 2; ++c) {
            const float* wr = w_hh + (16 * t + col) * H + 32 * c + 8 * q;
            half8 f;
#pragma unroll
            for (int j = 0; j < 8; ++j) f[j] = (_Float16)wr[j];
            wB[t][c] = f;
        }
    }

    // bpermute byte addresses for the octet pairs (loop-invariant)
    int adr0[4], adr1[4];
#pragma unroll
    for (int d = 0; d < 4; ++d) {
        adr0[d] = (8 * q + 2 * d) << 2;
        adr1[d] = (32 + 8 * q + 2 * d) << 2;
    }

    // gate parameters for hidden index = lane
    const float wih_r = w_ih[lane], wih_z = w_ih[H + lane], wih_n = w_ih[2 * H + lane];
    const float bsr = b_ih[lane] + b_hh[lane];              // merged r bias
    const float bsz = b_ih[H + lane] + b_hh[H + lane];      // merged z bias
    const float bin = b_ih[2 * H + lane];                   // n: keep split,
    const float bhn = b_hh[2 * H + lane];                   // r multiplies bhh_n

    float h_reg = 0.0f;
    const float* xb = x + (size_t)b * TSTEPS;

    const f32x4 Z = {0.f, 0.f, 0.f, 0.f};

    // x double-buffer
    float xc[XCHUNK], xn[XCHUNK];
#pragma unroll
    for (int k = 0; k < XCHUNK; ++k) xc[k] = xb[k];

    for (int tc = 0; tc < NCHUNK; ++tc) {
        const float* nb = xb + ((tc + 1 < NCHUNK) ? (tc + 1) * XCHUNK : 0);
#pragma unroll
        for (int k = 0; k < XCHUNK; ++k) xn[k] = nb[k];

#pragma unroll
        for (int tt = 0; tt < XCHUNK; ++tt) {
            // ---- register A-build: pair-pack + 8 bpermutes, no LDS ----
            const float hnb = dpp_rol1(h_reg);               // h_{i+1}
            const int pk = pack_f16_pair(h_reg, hnb);        // {h_i, h_{i+1}}

            uint4 a0, a1;
            a0.x = __builtin_amdgcn_ds_bpermute(adr0[0], pk);
            a0.y = __builtin_amdgcn_ds_bpermute(adr0[1], pk);
            a0.z = __builtin_amdgcn_ds_bpermute(adr0[2], pk);
            a0.w = __builtin_amdgcn_ds_bpermute(adr0[3], pk);
            a1.x = __builtin_amdgcn_ds_bpermute(adr1[0], pk);
            a1.y = __builtin_amdgcn_ds_bpermute(adr1[1], pk);
            a1.z = __builtin_amdgcn_ds_bpermute(adr1[2], pk);
            a1.w = __builtin_amdgcn_ds_bpermute(adr1[3], pk);
            const half8 A0 = __builtin_bit_cast(half8, a0);  // k = 8q..8q+7
            const half8 A1 = __builtin_bit_cast(half8, a1);  // k = 32+8q..

            const float xt = xc[tt];
            // input-projection terms: off the critical path
            const float ir = fmaf(xt, wih_r, bsr);
            const float iz = fmaf(xt, wih_z, bsz);
            const float in_ = fmaf(xt, wih_n, bin);

#define GEMV(t, d)                                                     \
            d = __builtin_amdgcn_mfma_f32_16x16x32_f16(A0, wB[t][0], Z, 0, 0, 0); \
            d = __builtin_amdgcn_mfma_f32_16x16x32_f16(A1, wB[t][1], d, 0, 0, 0);

            // ---- r tiles first: sigmoid overlaps the z/n MFMAs ----
            f32x4 d0, d1, d2, d3;
            GEMV(0, d0) GEMV(1, d1) GEMV(2, d2) GEMV(3, d3)
            const float ghr = (q < 2) ? (q == 0 ? d0[0] : d1[0])
                                      : (q == 2 ? d2[0] : d3[0]);
            const float r = fast_sigmoid(ir + ghr);

            f32x4 e0, e1, e2, e3;
            GEMV(4, e0) GEMV(5, e1) GEMV(6, e2) GEMV(7, e3)
            const float ghz = (q < 2) ? (q == 0 ? e0[0] : e1[0])
                                      : (q == 2 ? e2[0] : e3[0]);
            const float z = fast_sigmoid(iz + ghz);

            f32x4 g0, g1, g2, g3;
            GEMV(8, g0) GEMV(9, g1) GEMV(10, g2) GEMV(11, g3)
            const float ghn = (q < 2) ? (q == 0 ? g0[0] : g1[0])
                                      : (q == 2 ? g2[0] : g3[0]);
#undef GEMV

            const float n = fast_tanh(in_ + r * (ghn + bhn));
            h_reg = fmaf(z, h_reg - n, n);   // (1-z)*n + z*h
        }

#pragma unroll
        for (int k = 0; k < XCHUNK; ++k) xc[k] = xn[k];
    }

    // ---- head: out[b][c] = w_head[c,:] . h + b_head[c] ----
#pragma unroll
    for (int cc = 0; cc < CLASSES; ++cc) {
        float v = h_reg * w_head[cc * H + lane];
#pragma unroll
        for (int off = 32; off > 0; off >>= 1)
            v += __shfl_down(v, off, 64);
        if (lane == 0) out[b * CLASSES + cc] = v + b_head[cc];
    }
}

extern "C" void kernel_launch(void* const* d_in, const int* in_sizes, int n_in,
                              void* d_out, int out_size, void* d_ws, size_t ws_size,
                              hipStream_t stream) {
    const float* x      = (const float*)d_in[0];
    const float* w_ih   = (const float*)d_in[1];
    const float* w_hh   = (const float*)d_in[2];
    const float* b_ih   = (const float*)d_in[3];
    const float* b_hh   = (const float*)d_in[4];
    const float* w_head = (const float*)d_in[5];
    const float* b_head = (const float*)d_in[6];
    float* out = (float*)d_out;

    gru_mfma_bp_kernel<<<BATCH, 64, 0, stream>>>(x, w_ih, w_hh, b_ih, b_hh,
                                                 w_head, b_head, out);
}